// Round 1
// baseline (271.896 us; speedup 1.0000x reference)
//
#include <hip/hip_runtime.h>
#include <hip/hip_bf16.h>

#define B_ 32
#define T_ 256
#define D_ 64
#define H_ 128
#define G_ 384   // 3*H

typedef _Float16 half8 __attribute__((ext_vector_type(8)));
typedef _Float16 half4v __attribute__((ext_vector_type(4)));
typedef _Float16 half2v __attribute__((ext_vector_type(2)));
typedef float float4v __attribute__((ext_vector_type(4)));

__device__ __forceinline__ float fsigmoid(float x){ return 1.0f/(1.0f+__expf(-x)); }
__device__ __forceinline__ float ftanh_(float x){ return 1.0f - 2.0f/(1.0f+__expf(2.0f*x)); }

// NOTE (R5-R7 post-mortem): inputs/outputs are f32 (reference is jnp.float32;
// R1's on-device {0,1}-mask detector confirmed). bf16 misread was the NaN bug.
//
// Structure ledger (measured): R10's 1-barrier 4-wave chained-MFMA step was the
// minimum MFMA structure at ~1250 cyc/step vs ~466 cyc CU-level MFMA-issue
// floor (96 MFMAs/block/step, invariant under wave splits — mat-vec wastes
// 15/16 M-rows). R12: replace MFMA mat-vec with VALU v_dot2_f32_f16: 96
// dot2/lane/step issues in ~192 cyc PER SIMD (4 SIMDs concurrent), weights
// held in VGPRs, same 1-barrier/step skeleton.
#define BAR() do{ asm volatile("s_waitcnt lgkmcnt(0)" ::: "memory"); \
                  __builtin_amdgcn_s_barrier(); \
                  asm volatile("" ::: "memory"); } while(0)

// wcol[b,j] = column sums of the row-normalized adjacency (R1 derivation):
// adj_raw[i,j] = p_i p_j sim_ij + I; rs_i = 1 + p_i*sum_j p_j sim_ij;
// wcol_j = p_j * sum_i p_i sim_ij / rs_i + 1/rs_j  (sim symmetric).
// sim loop stays SCALAR with pitch 129: odd pitch puts the 4 quads' divergent
// i-rows on different banks -> conflict-free broadcast.
__global__ void __launch_bounds__(256) adj_k(const float* mm, const float* E,
                                             float* wcol){
  int b = blockIdx.x;
  int tid = threadIdx.x;
  int d = tid & 63, q = tid >> 6;
  __shared__ float spp[4][64];
  __shared__ float sp[64];
  __shared__ float sE[64*129];
  __shared__ float ssim[64*65];
  __shared__ float srs[64];
  float p = 0.0f;
  for (int t = q*64; t < q*64+64; t++) p += 1.0f - mm[(b*T_ + t)*D_ + d];
  spp[q][d] = p;
  for (int i = tid; i < D_*H_; i += 256){ int r = i >> 7, c = i & 127; sE[r*129+c] = E[i]; }
  __syncthreads();
  if (tid < 64) sp[tid] = (spp[0][tid]+spp[1][tid]+spp[2][tid]+spp[3][tid]) * (1.0f/T_);
  __syncthreads();
  float rowE[128];
  #pragma unroll
  for (int k = 0; k < 128; k++) rowE[k] = sE[d*129+k];
  for (int i = q*16; i < q*16+16; i++){
    float s = 0.0f;
    #pragma unroll
    for (int k = 0; k < 128; k++) s += rowE[k]*sE[i*129+k];
    ssim[d*65+i] = fmaxf(s, 0.0f);
  }
  __syncthreads();
  if (tid < 64){
    float rs = 0.0f;
    for (int j = 0; j < 64; j++) rs += sp[j]*ssim[tid*65+j];
    srs[tid] = fmaxf(sp[tid]*rs + 1.0f, 1e-6f);
  }
  __syncthreads();
  if (tid < 64){
    float s = 0.0f;
    for (int i = 0; i < 64; i++) s += sp[i]*ssim[tid*65+i]/srs[i];
    wcol[b*64 + tid] = sp[tid]*s + 1.0f/srs[tid];
  }
}

// gi_k v5: gi3 f16 (halves gi traffic); E staged into LDS f16 (pitch 132).
// Phase A: vr[32t][128h] = (x*(1-mm)*wcol/64)[32t][64d] x E[64d][128h] + time-enc
// Phase B: gi[32t][384g] = vr x W_ih^T + (bih + bhh[r,z]); gi3 transposed [b][g][t].
#define AVP 72
#define VRP 136
#define SEP 132
__global__ void __launch_bounds__(512,1) gi_k(const float* x, const float* mm,
                                              const float* vt, const float* E,
                                              const float* wih, const float* bih,
                                              const float* bhh, const float* wcol,
                                              _Float16* gi3){
  int bid = blockIdx.x;
  int b = bid >> 3, t0 = (bid & 7)*32;
  int tid = threadIdx.x;
  int w = tid >> 6, l = tid & 63;
  int lq = l >> 4, lm = l & 15;

  __shared__ __align__(16) _Float16 av[32*AVP];
  __shared__ __align__(16) _Float16 vrA[32*VRP];
  __shared__ __align__(16) _Float16 sEl[64*SEP];
  __shared__ float sVt[32];

  // stage av[t][d] = x*(1-mm)*wcol/64  (f32 in, f16 out)
  {
    int i = tid*4, t = i >> 6, d4 = i & 63;
    long src = (long)(b*T_ + t0 + t)*D_ + d4;
    float4 xv = *(const float4*)&x[src];
    float4 mv = *(const float4*)&mm[src];
    float4 wv = *(const float4*)&wcol[b*D_ + d4];
    half4v h;
    h[0]=(_Float16)(xv.x*(1.0f-mv.x)*wv.x*(1.0f/64));
    h[1]=(_Float16)(xv.y*(1.0f-mv.y)*wv.y*(1.0f/64));
    h[2]=(_Float16)(xv.z*(1.0f-mv.z)*wv.z*(1.0f/64));
    h[3]=(_Float16)(xv.w*(1.0f-mv.w)*wv.w*(1.0f/64));
    *(half4v*)&av[t*AVP + d4] = h;
  }
  // stage E -> LDS f16, coalesced
  {
    int r = tid >> 3, c0 = (tid & 7)*16;
    #pragma unroll
    for (int g = 0; g < 4; g++){
      float4 v = *(const float4*)&E[r*H_ + c0 + g*4];
      half4v h;
      h[0]=(_Float16)v.x; h[1]=(_Float16)v.y; h[2]=(_Float16)v.z; h[3]=(_Float16)v.w;
      *(half4v*)&sEl[r*SEP + c0 + g*4] = h;
    }
  }
  if (tid < 32) sVt[tid] = vt[b*T_ + t0 + tid];
  __syncthreads();

  // Phase A B-frags: B[k=d][n] = E[d][16w+n]  (gather from LDS)
  half8 bE[2];
  #pragma unroll
  for (int kc = 0; kc < 2; kc++){
    half8 f;
    #pragma unroll
    for (int jj = 0; jj < 8; jj++)
      f[jj] = sEl[(kc*32 + lq*8 + jj)*SEP + 16*w + lm];
    bE[kc] = f;
  }

  float4v accA[2] = {{0,0,0,0},{0,0,0,0}};
  #pragma unroll
  for (int kc = 0; kc < 2; kc++){
    #pragma unroll
    for (int mt = 0; mt < 2; mt++){
      half8 a = *(const half8*)&av[(mt*16+lm)*AVP + kc*32 + lq*8];
      accA[mt] = __builtin_amdgcn_mfma_f32_16x16x32_f16(a, bE[kc], accA[mt], 0,0,0);
    }
  }
  {
    int h = 16*w + lm;
    float fr = __expf(-(float)(h & 63) * 0.14391157f);   // ln(1e4)/64
    #pragma unroll
    for (int mt = 0; mt < 2; mt++){
      #pragma unroll
      for (int r = 0; r < 4; r++){
        int tl = mt*16 + lq*4 + r;
        float ang = sVt[tl] * fr;
        float e = (h < 64) ? __sinf(ang) : __cosf(ang);
        vrA[tl*VRP + h] = (_Float16)(accA[mt][r] + e);
      }
    }
  }
  __syncthreads();

  // Phase B: wave owns N-tiles 3w..3w+2
  half8 bW[3][4]; float biW[3];
  #pragma unroll
  for (int q = 0; q < 3; q++){
    int g = 16*(3*w + q) + lm;
    biW[q] = bih[g] + (g < 2*H_ ? bhh[g] : 0.0f);  // fold b_hh for r,z
    #pragma unroll
    for (int kc = 0; kc < 4; kc++){
      const float* src = &wih[(long)g*H_ + kc*32 + lq*8];
      float4 x0 = *(const float4*)src;
      float4 x1 = *(const float4*)(src+4);
      half8 f;
      f[0]=(_Float16)x0.x; f[1]=(_Float16)x0.y; f[2]=(_Float16)x0.z; f[3]=(_Float16)x0.w;
      f[4]=(_Float16)x1.x; f[5]=(_Float16)x1.y; f[6]=(_Float16)x1.z; f[7]=(_Float16)x1.w;
      bW[q][kc] = f;
    }
  }
  float4v cB[2][3];
  #pragma unroll
  for (int mt = 0; mt < 2; mt++)
    #pragma unroll
    for (int q = 0; q < 3; q++) cB[mt][q] = (float4v){0,0,0,0};
  #pragma unroll
  for (int kc = 0; kc < 4; kc++){
    #pragma unroll
    for (int mt = 0; mt < 2; mt++){
      half8 a = *(const half8*)&vrA[(mt*16+lm)*VRP + kc*32 + lq*8];
      #pragma unroll
      for (int q = 0; q < 3; q++)
        cB[mt][q] = __builtin_amdgcn_mfma_f32_16x16x32_f16(a, bW[q][kc], cB[mt][q], 0,0,0);
    }
  }
  #pragma unroll
  for (int mt = 0; mt < 2; mt++){
    #pragma unroll
    for (int q = 0; q < 3; q++){
      int g = 16*(3*w + q) + lm;
      int tb = t0 + mt*16 + lq*4;
      half4v hv;
      hv[0]=(_Float16)(cB[mt][q][0] + biW[q]); hv[1]=(_Float16)(cB[mt][q][1] + biW[q]);
      hv[2]=(_Float16)(cB[mt][q][2] + biW[q]); hv[3]=(_Float16)(cB[mt][q][3] + biW[q]);
      *(half4v*)&gi3[((long)(b*G_ + g))*T_ + tb] = hv;
    }
  }
}

// Sequential GRU v11 (R12): VALU-dot recurrence.
// The per-step mat-vec h[128] x W_hh^T[128,384] = 49K MACs. As MFMA (v10) this
// cost 96 MFMAs/step at CU-level throughput (~466 cyc floor, A-rows broadcast
// -> 15/16 wasted). As v_dot2_f32_f16 it is 96 insts/LANE/step (~192 cyc per
// SIMD, 4 SIMDs concurrent), weights resident in VGPRs (96 regs f16).
// Layout: lane pair (2j, 2j+1) owns gate row j; even lane k in [0,64),
// odd lane k in [64,128); slot s in {r,z,n} = W_hh row s*128+j.
// Pair-combine via one shfl_xor(1) per slot; gate math + h write on even
// lanes only. Same 1-barrier/step, hb[2] f16 ping-pong, 8-step gi prefetch.
__global__ void __launch_bounds__(256,1) gru_k(const _Float16* gi3, const float* whh,
                                               const float* bhh, const int* lengths,
                                               float* out){
  int b = blockIdx.x;
  int tid = threadIdx.x;
  int j  = tid >> 1;          // gate row within H, 0..127
  int kh = tid & 1;           // k-half: [kh*64, kh*64+64)
  int len = lengths[b];
  bool even = (kh == 0);

  __shared__ __align__(16) _Float16 hb[2][H_];

  // Weights in registers: Wr[s][q] pairs with h[kh*64 + 2q, 2q+1]
  half2v Wr[3][32];
  #pragma unroll
  for (int s = 0; s < 3; s++){
    const float* src = &whh[(long)(s*H_ + j)*H_ + kh*64];
    #pragma unroll
    for (int q4 = 0; q4 < 16; q4++){
      float4 v = *(const float4*)(src + q4*4);
      half2v a, c;
      a[0]=(_Float16)v.x; a[1]=(_Float16)v.y;
      c[0]=(_Float16)v.z; c[1]=(_Float16)v.w;
      Wr[s][2*q4]   = a;
      Wr[s][2*q4+1] = c;
    }
  }
  float bn_ = bhh[2*H_ + j];
  const _Float16* pr = gi3 + ((long)b*G_ + j)*T_;
  const _Float16* pz = pr + (long)H_*T_;
  const _Float16* pn = pr + (long)2*H_*T_;

  if (tid < H_){ hb[0][tid] = (_Float16)0.0f; hb[1][tid] = (_Float16)0.0f; }

  float gr[2][8], gz[2][8], gn[2][8];
  if (even){
    half8 a = *(const half8*)(pr);
    half8 bv = *(const half8*)(pz);
    half8 cv = *(const half8*)(pn);
    #pragma unroll
    for (int i = 0; i < 8; i++){ gr[0][i]=(float)a[i]; gz[0][i]=(float)bv[i]; gn[0][i]=(float)cv[i]; }
  }
  __syncthreads();   // cold path: full barrier fine

  float hval = 0.0f;
  float ho[8];
  int cb = 0;
  for (int c = 0; c < 32; c++){
    if (even && c+1 < 32){
      int nb2 = (c+1)*8;
      half8 a = *(const half8*)(pr+nb2);
      half8 bv = *(const half8*)(pz+nb2);
      half8 cv = *(const half8*)(pn+nb2);
      int nc = cb^1;
      #pragma unroll
      for (int i = 0; i < 8; i++){ gr[nc][i]=(float)a[i]; gz[nc][i]=(float)bv[i]; gn[nc][i]=(float)cv[i]; }
    }
    #pragma unroll
    for (int i = 0; i < 8; i++){
      int rp = i & 1;            // read hb[rp], write hb[rp^1]
      // 6 accumulators: 3 slots x 2 sub-chains (hide fdot2 dep latency)
      float a0[2] = {0.0f, 0.0f};
      float a1[2] = {0.0f, 0.0f};
      float a2[2] = {0.0f, 0.0f};
      #pragma unroll
      for (int q8 = 0; q8 < 8; q8++){
        half8 hv = *(const half8*)&hb[rp][kh*64 + q8*8];   // 2-addr broadcast read
        #pragma unroll
        for (int m = 0; m < 4; m++){
          half2v hh; hh[0] = hv[2*m]; hh[1] = hv[2*m+1];
          int q = q8*4 + m, u = q & 1;
          a0[u] = __builtin_amdgcn_fdot2(hh, Wr[0][q], a0[u], false);
          a1[u] = __builtin_amdgcn_fdot2(hh, Wr[1][q], a1[u], false);
          a2[u] = __builtin_amdgcn_fdot2(hh, Wr[2][q], a2[u], false);
        }
      }
      float R = a0[0] + a0[1];
      float Z = a1[0] + a1[1];
      float N = a2[0] + a2[1];
      R += __shfl_xor(R, 1, 64);   // combine k-halves across the lane pair
      Z += __shfl_xor(Z, 1, 64);
      N += __shfl_xor(N, 1, 64);
      if (even){
        float r = fsigmoid(gr[cb][i] + R);
        float z = fsigmoid(gz[cb][i] + Z);
        float n = ftanh_(gn[cb][i] + r*(N + bn_));
        hval = (1.0f - z)*n + z*hval;
        hb[rp^1][j] = (_Float16)hval;
        ho[i] = (c*8 + i < len) ? hval : 0.0f;
      }
      BAR();
    }
    if (even){
      long ob = ((long)b*T_ + c*8)*H_ + j;
      #pragma unroll
      for (int i = 0; i < 8; i++) out[ob + (long)i*H_] = ho[i];
    }
    cb ^= 1;
  }
}

extern "C" void kernel_launch(void* const* d_in, const int* in_sizes, int n_in,
                              void* d_out, int out_size, void* d_ws, size_t ws_size,
                              hipStream_t stream) {
  char* base = (char*)d_ws;
  size_t off = 0;
  auto alloc = [&](size_t bytes)->void*{
    void* p = base + off; off = (off + bytes + 255) & ~(size_t)255; return p;
  };
  float*     wcol = (float*)alloc((size_t)B_*D_*4);
  _Float16*  gi3  = (_Float16*)alloc((size_t)B_*G_*T_*2);
  if (off > ws_size) return;

  const float* x   = (const float*)d_in[0];
  const float* mm  = (const float*)d_in[1];
  const float* vt  = (const float*)d_in[2];
  const int*   len = (const int*)d_in[4];
  const float* E   = (const float*)d_in[5];
  const float* wih = (const float*)d_in[6];
  const float* whh = (const float*)d_in[7];
  const float* bih = (const float*)d_in[8];
  const float* bhh = (const float*)d_in[9];

  adj_k<<<dim3(B_),dim3(256),0,stream>>>(mm, E, wcol);
  gi_k<<<dim3(256),dim3(512),0,stream>>>(x, mm, vt, E, wih, bih, bhh, wcol, gi3);
  gru_k<<<dim3(B_),dim3(256),0,stream>>>(gi3, whh, bhh, len, (float*)d_out);
}

// Round 2
// 264.393 us; speedup vs baseline: 1.0284x; 1.0284x over previous
//
#include <hip/hip_runtime.h>
#include <hip/hip_bf16.h>

#define B_ 32
#define T_ 256
#define D_ 64
#define H_ 128
#define G_ 384   // 3*H

typedef _Float16 half8 __attribute__((ext_vector_type(8)));
typedef _Float16 half4v __attribute__((ext_vector_type(4)));
typedef _Float16 half2v __attribute__((ext_vector_type(2)));
typedef float float4v __attribute__((ext_vector_type(4)));

__device__ __forceinline__ float fsigmoid(float x){ return 1.0f/(1.0f+__expf(-x)); }
__device__ __forceinline__ float ftanh_(float x){ return 1.0f - 2.0f/(1.0f+__expf(2.0f*x)); }

// NOTE (R5-R7 post-mortem): inputs/outputs are f32. bf16 misread was the NaN bug.
//
// Structure ledger (measured):
//  - v10 (R10): 1-barrier 4-wave chained-MFMA step = 1241 cyc/step (132.4 us).
//    96 MFMAs/step (mat-vec, 15/16 M-rows wasted) = ~400-470 cyc CU-serial
//    in-chain; rest = ds_read latency + gate transcendental chain + barrier.
//  - v11 (R12): fdot2 lane-pair(xor1) = 1411 cyc/step (150.5 us) REGRESSION.
//    Cause: gr[cb][i] runtime-indexed -> scratch (VGPR 124 < 144 static need,
//    rule #20) + 3 serial shfl_xor(1) before gates. fdot2 concept not refuted.
//  - v12 (R13, this): fdot2 k-split pair (l, l+32) per gate row; uniform
//    96 fdot2/lane; 3x shfl_xor(32) combine; named double-buffer regs, zero
//    runtime indexing; same 1-BAR/step skeleton.
#define BAR() do{ asm volatile("s_waitcnt lgkmcnt(0)" ::: "memory"); \
                  __builtin_amdgcn_s_barrier(); \
                  asm volatile("" ::: "memory"); } while(0)

// wcol[b,j] = column sums of the row-normalized adjacency (R1 derivation):
// adj_raw[i,j] = p_i p_j sim_ij + I; rs_i = 1 + p_i*sum_j p_j sim_ij;
// wcol_j = p_j * sum_i p_i sim_ij / rs_i + 1/rs_j  (sim symmetric).
__global__ void __launch_bounds__(256) adj_k(const float* mm, const float* E,
                                             float* wcol){
  int b = blockIdx.x;
  int tid = threadIdx.x;
  int d = tid & 63, q = tid >> 6;
  __shared__ float spp[4][64];
  __shared__ float sp[64];
  __shared__ float sE[64*129];
  __shared__ float ssim[64*65];
  __shared__ float srs[64];
  float p = 0.0f;
  for (int t = q*64; t < q*64+64; t++) p += 1.0f - mm[(b*T_ + t)*D_ + d];
  spp[q][d] = p;
  for (int i = tid; i < D_*H_; i += 256){ int r = i >> 7, c = i & 127; sE[r*129+c] = E[i]; }
  __syncthreads();
  if (tid < 64) sp[tid] = (spp[0][tid]+spp[1][tid]+spp[2][tid]+spp[3][tid]) * (1.0f/T_);
  __syncthreads();
  float rowE[128];
  #pragma unroll
  for (int k = 0; k < 128; k++) rowE[k] = sE[d*129+k];
  for (int i = q*16; i < q*16+16; i++){
    float s = 0.0f;
    #pragma unroll
    for (int k = 0; k < 128; k++) s += rowE[k]*sE[i*129+k];
    ssim[d*65+i] = fmaxf(s, 0.0f);
  }
  __syncthreads();
  if (tid < 64){
    float rs = 0.0f;
    for (int j = 0; j < 64; j++) rs += sp[j]*ssim[tid*65+j];
    srs[tid] = fmaxf(sp[tid]*rs + 1.0f, 1e-6f);
  }
  __syncthreads();
  if (tid < 64){
    float s = 0.0f;
    for (int i = 0; i < 64; i++) s += sp[i]*ssim[tid*65+i]/srs[i];
    wcol[b*64 + tid] = sp[tid]*s + 1.0f/srs[tid];
  }
}

// gi_k v5: gi3 f16 (halves gi traffic); E staged into LDS f16 (pitch 132).
// Phase A: vr[32t][128h] = (x*(1-mm)*wcol/64)[32t][64d] x E[64d][128h] + time-enc
// Phase B: gi[32t][384g] = vr x W_ih^T + (bih + bhh[r,z]); gi3 transposed [b][g][t].
#define AVP 72
#define VRP 136
#define SEP 132
__global__ void __launch_bounds__(512,1) gi_k(const float* x, const float* mm,
                                              const float* vt, const float* E,
                                              const float* wih, const float* bih,
                                              const float* bhh, const float* wcol,
                                              _Float16* gi3){
  int bid = blockIdx.x;
  int b = bid >> 3, t0 = (bid & 7)*32;
  int tid = threadIdx.x;
  int w = tid >> 6, l = tid & 63;
  int lq = l >> 4, lm = l & 15;

  __shared__ __align__(16) _Float16 av[32*AVP];
  __shared__ __align__(16) _Float16 vrA[32*VRP];
  __shared__ __align__(16) _Float16 sEl[64*SEP];
  __shared__ float sVt[32];

  // stage av[t][d] = x*(1-mm)*wcol/64  (f32 in, f16 out)
  {
    int i = tid*4, t = i >> 6, d4 = i & 63;
    long src = (long)(b*T_ + t0 + t)*D_ + d4;
    float4 xv = *(const float4*)&x[src];
    float4 mv = *(const float4*)&mm[src];
    float4 wv = *(const float4*)&wcol[b*D_ + d4];
    half4v h;
    h[0]=(_Float16)(xv.x*(1.0f-mv.x)*wv.x*(1.0f/64));
    h[1]=(_Float16)(xv.y*(1.0f-mv.y)*wv.y*(1.0f/64));
    h[2]=(_Float16)(xv.z*(1.0f-mv.z)*wv.z*(1.0f/64));
    h[3]=(_Float16)(xv.w*(1.0f-mv.w)*wv.w*(1.0f/64));
    *(half4v*)&av[t*AVP + d4] = h;
  }
  // stage E -> LDS f16, coalesced
  {
    int r = tid >> 3, c0 = (tid & 7)*16;
    #pragma unroll
    for (int g = 0; g < 4; g++){
      float4 v = *(const float4*)&E[r*H_ + c0 + g*4];
      half4v h;
      h[0]=(_Float16)v.x; h[1]=(_Float16)v.y; h[2]=(_Float16)v.z; h[3]=(_Float16)v.w;
      *(half4v*)&sEl[r*SEP + c0 + g*4] = h;
    }
  }
  if (tid < 32) sVt[tid] = vt[b*T_ + t0 + tid];
  __syncthreads();

  // Phase A B-frags: B[k=d][n] = E[d][16w+n]  (gather from LDS)
  half8 bE[2];
  #pragma unroll
  for (int kc = 0; kc < 2; kc++){
    half8 f;
    #pragma unroll
    for (int jj = 0; jj < 8; jj++)
      f[jj] = sEl[(kc*32 + lq*8 + jj)*SEP + 16*w + lm];
    bE[kc] = f;
  }

  float4v accA[2] = {{0,0,0,0},{0,0,0,0}};
  #pragma unroll
  for (int kc = 0; kc < 2; kc++){
    #pragma unroll
    for (int mt = 0; mt < 2; mt++){
      half8 a = *(const half8*)&av[(mt*16+lm)*AVP + kc*32 + lq*8];
      accA[mt] = __builtin_amdgcn_mfma_f32_16x16x32_f16(a, bE[kc], accA[mt], 0,0,0);
    }
  }
  {
    int h = 16*w + lm;
    float fr = __expf(-(float)(h & 63) * 0.14391157f);   // ln(1e4)/64
    #pragma unroll
    for (int mt = 0; mt < 2; mt++){
      #pragma unroll
      for (int r = 0; r < 4; r++){
        int tl = mt*16 + lq*4 + r;
        float ang = sVt[tl] * fr;
        float e = (h < 64) ? __sinf(ang) : __cosf(ang);
        vrA[tl*VRP + h] = (_Float16)(accA[mt][r] + e);
      }
    }
  }
  __syncthreads();

  // Phase B: wave owns N-tiles 3w..3w+2
  half8 bW[3][4]; float biW[3];
  #pragma unroll
  for (int q = 0; q < 3; q++){
    int g = 16*(3*w + q) + lm;
    biW[q] = bih[g] + (g < 2*H_ ? bhh[g] : 0.0f);  // fold b_hh for r,z
    #pragma unroll
    for (int kc = 0; kc < 4; kc++){
      const float* src = &wih[(long)g*H_ + kc*32 + lq*8];
      float4 x0 = *(const float4*)src;
      float4 x1 = *(const float4*)(src+4);
      half8 f;
      f[0]=(_Float16)x0.x; f[1]=(_Float16)x0.y; f[2]=(_Float16)x0.z; f[3]=(_Float16)x0.w;
      f[4]=(_Float16)x1.x; f[5]=(_Float16)x1.y; f[6]=(_Float16)x1.z; f[7]=(_Float16)x1.w;
      bW[q][kc] = f;
    }
  }
  float4v cB[2][3];
  #pragma unroll
  for (int mt = 0; mt < 2; mt++)
    #pragma unroll
    for (int q = 0; q < 3; q++) cB[mt][q] = (float4v){0,0,0,0};
  #pragma unroll
  for (int kc = 0; kc < 4; kc++){
    #pragma unroll
    for (int mt = 0; mt < 2; mt++){
      half8 a = *(const half8*)&vrA[(mt*16+lm)*VRP + kc*32 + lq*8];
      #pragma unroll
      for (int q = 0; q < 3; q++)
        cB[mt][q] = __builtin_amdgcn_mfma_f32_16x16x32_f16(a, bW[q][kc], cB[mt][q], 0,0,0);
    }
  }
  #pragma unroll
  for (int mt = 0; mt < 2; mt++){
    #pragma unroll
    for (int q = 0; q < 3; q++){
      int g = 16*(3*w + q) + lm;
      int tb = t0 + mt*16 + lq*4;
      half4v hv;
      hv[0]=(_Float16)(cB[mt][q][0] + biW[q]); hv[1]=(_Float16)(cB[mt][q][1] + biW[q]);
      hv[2]=(_Float16)(cB[mt][q][2] + biW[q]); hv[3]=(_Float16)(cB[mt][q][3] + biW[q]);
      *(half4v*)&gi3[((long)(b*G_ + g))*T_ + tb] = hv;
    }
  }
}

// Sequential GRU v12 (R13): k-split fdot2 recurrence.
// Lane l and l+32 of wave w co-own gate row j = 32w + (l&31): lane reduces
// k in [kh*64, kh*64+64) for ALL THREE gates (32 half2 x 3 = 96 fdot2/lane,
// uniform, balanced). Pair-combine via 3x shfl_xor(32); gate math + h write
// on the kh==0 half-wave. One LDS-only BAR per step, hb[2] f16 ping-pong.
// All buffers statically indexed (v11's cb-indexed arrays went to scratch).
__global__ void __launch_bounds__(256,1) gru_k(const _Float16* gi3, const float* whh,
                                               const float* bhh, const int* lengths,
                                               float* out){
  int b = blockIdx.x;
  int tid = threadIdx.x;
  int w = tid >> 6, l = tid & 63;
  int kh = l >> 5;               // this lane's k-half
  int j  = 32*w + (l & 31);      // gate row owned by the (l, l+32) pair
  bool lo = (kh == 0);
  int len = lengths[b];

  __shared__ __align__(16) _Float16 hb[2][H_];

  // Weights in registers: rows {j, H+j, 2H+j}, k in [kh*64, kh*64+64)
  half2v Wr[32], Wz[32], Wn[32];
  {
    const float* baseR = &whh[(long)j*H_        + kh*64];
    const float* baseZ = &whh[(long)(H_ + j)*H_ + kh*64];
    const float* baseN = &whh[(long)(2*H_+j)*H_ + kh*64];
    #pragma unroll
    for (int t4 = 0; t4 < 16; t4++){
      float4 vr = *(const float4*)(baseR + t4*4);
      float4 vz = *(const float4*)(baseZ + t4*4);
      float4 vn = *(const float4*)(baseN + t4*4);
      half2v a;
      a[0]=(_Float16)vr.x; a[1]=(_Float16)vr.y; Wr[2*t4] = a;
      a[0]=(_Float16)vr.z; a[1]=(_Float16)vr.w; Wr[2*t4+1] = a;
      a[0]=(_Float16)vz.x; a[1]=(_Float16)vz.y; Wz[2*t4] = a;
      a[0]=(_Float16)vz.z; a[1]=(_Float16)vz.w; Wz[2*t4+1] = a;
      a[0]=(_Float16)vn.x; a[1]=(_Float16)vn.y; Wn[2*t4] = a;
      a[0]=(_Float16)vn.z; a[1]=(_Float16)vn.w; Wn[2*t4+1] = a;
    }
  }
  float bn_ = bhh[2*H_ + j];
  const _Float16* pr = gi3 + ((long)b*G_ + j)*T_;
  const _Float16* pz = pr + (long)H_*T_;
  const _Float16* pn = pr + (long)2*H_*T_;

  if (tid < H_){ hb[0][tid] = (_Float16)0.0f; hb[1][tid] = (_Float16)0.0f; }

  // gi prefetch: named double-buffer registers, static (no runtime indexing)
  half8 prA, pzA, pnA, prB, pzB, pnB;
  if (lo){
    prA = *(const half8*)pr; pzA = *(const half8*)pz; pnA = *(const half8*)pn;
  }
  __syncthreads();

  float hval = 0.0f;

  auto substeps = [&](half8 cr, half8 cz, half8 cn, int c){
    float ho[8];
    #pragma unroll
    for (int i = 0; i < 8; i++){
      const int rp = i & 1;            // read hb[rp], write hb[rp^1]
      float ar0=0.0f, ar1=0.0f, az0=0.0f, az1=0.0f, an0=0.0f, an1=0.0f;
      #pragma unroll
      for (int q8 = 0; q8 < 8; q8++){
        half8 hv = *(const half8*)&hb[rp][kh*64 + q8*8];   // 2 addrs/wave, broadcast
        #pragma unroll
        for (int m = 0; m < 4; m++){
          half2v h2; h2[0] = hv[2*m]; h2[1] = hv[2*m+1];
          const int q = q8*4 + m;
          if ((q & 1) == 0){
            ar0 = __builtin_amdgcn_fdot2(h2, Wr[q], ar0, false);
            az0 = __builtin_amdgcn_fdot2(h2, Wz[q], az0, false);
            an0 = __builtin_amdgcn_fdot2(h2, Wn[q], an0, false);
          } else {
            ar1 = __builtin_amdgcn_fdot2(h2, Wr[q], ar1, false);
            az1 = __builtin_amdgcn_fdot2(h2, Wz[q], az1, false);
            an1 = __builtin_amdgcn_fdot2(h2, Wn[q], an1, false);
          }
        }
      }
      float R = ar0 + ar1, Z = az0 + az1, N = an0 + an1;
      R += __shfl_xor(R, 32, 64);      // combine k-halves across the pair
      Z += __shfl_xor(Z, 32, 64);
      N += __shfl_xor(N, 32, 64);
      if (lo){
        float r = fsigmoid((float)cr[i] + R);
        float z = fsigmoid((float)cz[i] + Z);
        float n = ftanh_((float)cn[i] + r*(N + bn_));
        hval = (1.0f - z)*n + z*hval;
        hb[rp^1][j] = (_Float16)hval;
        ho[i] = (c*8 + i < len) ? hval : 0.0f;
      }
      BAR();
    }
    if (lo){
      long ob = ((long)b*T_ + c*8)*H_ + j;
      #pragma unroll
      for (int i = 0; i < 8; i++) out[ob + (long)i*H_] = ho[i];
    }
  };

  for (int c = 0; c < 32; c += 2){
    if (lo){
      int nb = (c+1)*8;
      prB = *(const half8*)(pr+nb); pzB = *(const half8*)(pz+nb); pnB = *(const half8*)(pn+nb);
    }
    substeps(prA, pzA, pnA, c);
    if (lo && c+2 < 32){
      int nb = (c+2)*8;
      prA = *(const half8*)(pr+nb); pzA = *(const half8*)(pz+nb); pnA = *(const half8*)(pn+nb);
    }
    substeps(prB, pzB, pnB, c+1);
  }
}

extern "C" void kernel_launch(void* const* d_in, const int* in_sizes, int n_in,
                              void* d_out, int out_size, void* d_ws, size_t ws_size,
                              hipStream_t stream) {
  char* base = (char*)d_ws;
  size_t off = 0;
  auto alloc = [&](size_t bytes)->void*{
    void* p = base + off; off = (off + bytes + 255) & ~(size_t)255; return p;
  };
  float*     wcol = (float*)alloc((size_t)B_*D_*4);
  _Float16*  gi3  = (_Float16*)alloc((size_t)B_*G_*T_*2);
  if (off > ws_size) return;

  const float* x   = (const float*)d_in[0];
  const float* mm  = (const float*)d_in[1];
  const float* vt  = (const float*)d_in[2];
  const int*   len = (const int*)d_in[4];
  const float* E   = (const float*)d_in[5];
  const float* wih = (const float*)d_in[6];
  const float* whh = (const float*)d_in[7];
  const float* bih = (const float*)d_in[8];
  const float* bhh = (const float*)d_in[9];

  adj_k<<<dim3(B_),dim3(256),0,stream>>>(mm, E, wcol);
  gi_k<<<dim3(256),dim3(512),0,stream>>>(x, mm, vt, E, wih, bih, bhh, wcol, gi3);
  gru_k<<<dim3(B_),dim3(256),0,stream>>>(gi3, whh, bhh, len, (float*)d_out);
}

// Round 3
// 260.254 us; speedup vs baseline: 1.0447x; 1.0159x over previous
//
#include <hip/hip_runtime.h>
#include <hip/hip_bf16.h>

#define B_ 32
#define T_ 256
#define D_ 64
#define H_ 128
#define G_ 384   // 3*H

typedef _Float16 half8 __attribute__((ext_vector_type(8)));
typedef _Float16 half4v __attribute__((ext_vector_type(4)));
typedef _Float16 half2v __attribute__((ext_vector_type(2)));
typedef float float4v __attribute__((ext_vector_type(4)));

__device__ __forceinline__ float fsigmoid(float x){ return 1.0f/(1.0f+__expf(-x)); }
__device__ __forceinline__ float ftanh_(float x){ return 1.0f - 2.0f/(1.0f+__expf(2.0f*x)); }

// NOTE (R5-R7 post-mortem): inputs/outputs are f32. bf16 misread was the NaN bug.
//
// Structure ledger (measured):
//  - v10 (R10): 1-barrier 4-wave chained-MFMA step = 1241 cyc/step (132.4 us).
//    96 MFMAs/step (mat-vec, 15/16 M-rows wasted) = ~466 cyc CU-serial issue
//    floor; rest = ds_read latency + gate chain + barrier. VGPR 140 resident OK.
//  - v11 (R12): fdot2 lane-pair(xor1) = 1411 cyc/step (150.5 us) REGRESSION.
//  - v12 (R13): fdot2 k-split pair (xor32) = ~1320 cyc/step (141 us). VGPR=108
//    vs ~150 static need -> allocator discarded weight regs (remat/AGPR-park);
//    VALUBusy(active)~50% = ~660 cyc/step vs ~240 modeled = reload traffic.
//  - v13 (R14, this): v12 + anti-remat asm pins on all 96 weight VGPRs + lean
//    regs (no ho[8], immediate out store). Diagnostic: VGPR_Count must rise to
//    ~150+; if it reverts to ~108 the fdot2 line is dead.
#define BAR() do{ asm volatile("s_waitcnt lgkmcnt(0)" ::: "memory"); \
                  __builtin_amdgcn_s_barrier(); \
                  asm volatile("" ::: "memory"); } while(0)

// wcol[b,j] = column sums of the row-normalized adjacency (R1 derivation):
// adj_raw[i,j] = p_i p_j sim_ij + I; rs_i = 1 + p_i*sum_j p_j sim_ij;
// wcol_j = p_j * sum_i p_i sim_ij / rs_i + 1/rs_j  (sim symmetric).
__global__ void __launch_bounds__(256) adj_k(const float* mm, const float* E,
                                             float* wcol){
  int b = blockIdx.x;
  int tid = threadIdx.x;
  int d = tid & 63, q = tid >> 6;
  __shared__ float spp[4][64];
  __shared__ float sp[64];
  __shared__ float sE[64*129];
  __shared__ float ssim[64*65];
  __shared__ float srs[64];
  float p = 0.0f;
  for (int t = q*64; t < q*64+64; t++) p += 1.0f - mm[(b*T_ + t)*D_ + d];
  spp[q][d] = p;
  for (int i = tid; i < D_*H_; i += 256){ int r = i >> 7, c = i & 127; sE[r*129+c] = E[i]; }
  __syncthreads();
  if (tid < 64) sp[tid] = (spp[0][tid]+spp[1][tid]+spp[2][tid]+spp[3][tid]) * (1.0f/T_);
  __syncthreads();
  float rowE[128];
  #pragma unroll
  for (int k = 0; k < 128; k++) rowE[k] = sE[d*129+k];
  for (int i = q*16; i < q*16+16; i++){
    float s = 0.0f;
    #pragma unroll
    for (int k = 0; k < 128; k++) s += rowE[k]*sE[i*129+k];
    ssim[d*65+i] = fmaxf(s, 0.0f);
  }
  __syncthreads();
  if (tid < 64){
    float rs = 0.0f;
    for (int j = 0; j < 64; j++) rs += sp[j]*ssim[tid*65+j];
    srs[tid] = fmaxf(sp[tid]*rs + 1.0f, 1e-6f);
  }
  __syncthreads();
  if (tid < 64){
    float s = 0.0f;
    for (int i = 0; i < 64; i++) s += sp[i]*ssim[tid*65+i]/srs[i];
    wcol[b*64 + tid] = sp[tid]*s + 1.0f/srs[tid];
  }
}

// gi_k v5: gi3 f16 (halves gi traffic); E staged into LDS f16 (pitch 132).
// Phase A: vr[32t][128h] = (x*(1-mm)*wcol/64)[32t][64d] x E[64d][128h] + time-enc
// Phase B: gi[32t][384g] = vr x W_ih^T + (bih + bhh[r,z]); gi3 transposed [b][g][t].
#define AVP 72
#define VRP 136
#define SEP 132
__global__ void __launch_bounds__(512,1) gi_k(const float* x, const float* mm,
                                              const float* vt, const float* E,
                                              const float* wih, const float* bih,
                                              const float* bhh, const float* wcol,
                                              _Float16* gi3){
  int bid = blockIdx.x;
  int b = bid >> 3, t0 = (bid & 7)*32;
  int tid = threadIdx.x;
  int w = tid >> 6, l = tid & 63;
  int lq = l >> 4, lm = l & 15;

  __shared__ __align__(16) _Float16 av[32*AVP];
  __shared__ __align__(16) _Float16 vrA[32*VRP];
  __shared__ __align__(16) _Float16 sEl[64*SEP];
  __shared__ float sVt[32];

  // stage av[t][d] = x*(1-mm)*wcol/64  (f32 in, f16 out)
  {
    int i = tid*4, t = i >> 6, d4 = i & 63;
    long src = (long)(b*T_ + t0 + t)*D_ + d4;
    float4 xv = *(const float4*)&x[src];
    float4 mv = *(const float4*)&mm[src];
    float4 wv = *(const float4*)&wcol[b*D_ + d4];
    half4v h;
    h[0]=(_Float16)(xv.x*(1.0f-mv.x)*wv.x*(1.0f/64));
    h[1]=(_Float16)(xv.y*(1.0f-mv.y)*wv.y*(1.0f/64));
    h[2]=(_Float16)(xv.z*(1.0f-mv.z)*wv.z*(1.0f/64));
    h[3]=(_Float16)(xv.w*(1.0f-mv.w)*wv.w*(1.0f/64));
    *(half4v*)&av[t*AVP + d4] = h;
  }
  // stage E -> LDS f16, coalesced
  {
    int r = tid >> 3, c0 = (tid & 7)*16;
    #pragma unroll
    for (int g = 0; g < 4; g++){
      float4 v = *(const float4*)&E[r*H_ + c0 + g*4];
      half4v h;
      h[0]=(_Float16)v.x; h[1]=(_Float16)v.y; h[2]=(_Float16)v.z; h[3]=(_Float16)v.w;
      *(half4v*)&sEl[r*SEP + c0 + g*4] = h;
    }
  }
  if (tid < 32) sVt[tid] = vt[b*T_ + t0 + tid];
  __syncthreads();

  // Phase A B-frags: B[k=d][n] = E[d][16w+n]  (gather from LDS)
  half8 bE[2];
  #pragma unroll
  for (int kc = 0; kc < 2; kc++){
    half8 f;
    #pragma unroll
    for (int jj = 0; jj < 8; jj++)
      f[jj] = sEl[(kc*32 + lq*8 + jj)*SEP + 16*w + lm];
    bE[kc] = f;
  }

  float4v accA[2] = {{0,0,0,0},{0,0,0,0}};
  #pragma unroll
  for (int kc = 0; kc < 2; kc++){
    #pragma unroll
    for (int mt = 0; mt < 2; mt++){
      half8 a = *(const half8*)&av[(mt*16+lm)*AVP + kc*32 + lq*8];
      accA[mt] = __builtin_amdgcn_mfma_f32_16x16x32_f16(a, bE[kc], accA[mt], 0,0,0);
    }
  }
  {
    int h = 16*w + lm;
    float fr = __expf(-(float)(h & 63) * 0.14391157f);   // ln(1e4)/64
    #pragma unroll
    for (int mt = 0; mt < 2; mt++){
      #pragma unroll
      for (int r = 0; r < 4; r++){
        int tl = mt*16 + lq*4 + r;
        float ang = sVt[tl] * fr;
        float e = (h < 64) ? __sinf(ang) : __cosf(ang);
        vrA[tl*VRP + h] = (_Float16)(accA[mt][r] + e);
      }
    }
  }
  __syncthreads();

  // Phase B: wave owns N-tiles 3w..3w+2
  half8 bW[3][4]; float biW[3];
  #pragma unroll
  for (int q = 0; q < 3; q++){
    int g = 16*(3*w + q) + lm;
    biW[q] = bih[g] + (g < 2*H_ ? bhh[g] : 0.0f);  // fold b_hh for r,z
    #pragma unroll
    for (int kc = 0; kc < 4; kc++){
      const float* src = &wih[(long)g*H_ + kc*32 + lq*8];
      float4 x0 = *(const float4*)src;
      float4 x1 = *(const float4*)(src+4);
      half8 f;
      f[0]=(_Float16)x0.x; f[1]=(_Float16)x0.y; f[2]=(_Float16)x0.z; f[3]=(_Float16)x0.w;
      f[4]=(_Float16)x1.x; f[5]=(_Float16)x1.y; f[6]=(_Float16)x1.z; f[7]=(_Float16)x1.w;
      bW[q][kc] = f;
    }
  }
  float4v cB[2][3];
  #pragma unroll
  for (int mt = 0; mt < 2; mt++)
    #pragma unroll
    for (int q = 0; q < 3; q++) cB[mt][q] = (float4v){0,0,0,0};
  #pragma unroll
  for (int kc = 0; kc < 4; kc++){
    #pragma unroll
    for (int mt = 0; mt < 2; mt++){
      half8 a = *(const half8*)&vrA[(mt*16+lm)*VRP + kc*32 + lq*8];
      #pragma unroll
      for (int q = 0; q < 3; q++)
        cB[mt][q] = __builtin_amdgcn_mfma_f32_16x16x32_f16(a, bW[q][kc], cB[mt][q], 0,0,0);
    }
  }
  #pragma unroll
  for (int mt = 0; mt < 2; mt++){
    #pragma unroll
    for (int q = 0; q < 3; q++){
      int g = 16*(3*w + q) + lm;
      int tb = t0 + mt*16 + lq*4;
      half4v hv;
      hv[0]=(_Float16)(cB[mt][q][0] + biW[q]); hv[1]=(_Float16)(cB[mt][q][1] + biW[q]);
      hv[2]=(_Float16)(cB[mt][q][2] + biW[q]); hv[3]=(_Float16)(cB[mt][q][3] + biW[q]);
      *(half4v*)&gi3[((long)(b*G_ + g))*T_ + tb] = hv;
    }
  }
}

// Sequential GRU v13 (R14): k-split fdot2 + anti-remat pins.
// Lane l and l+32 of wave w co-own gate row j = 32w + (l&31): lane reduces
// k in [kh*64, kh*64+64) for all three gates (96 fdot2/lane). Pair-combine
// via 3x shfl_xor(32); gate math + h write + immediate out store on kh==0.
// Weights pinned in VGPRs via opaque asm (kills rematerialization/AGPR-park
// that poisoned v11/v12). One LDS-only BAR per step, hb[2] f16 ping-pong.
__global__ void __launch_bounds__(256,1) gru_k(const _Float16* gi3, const float* whh,
                                               const float* bhh, const int* lengths,
                                               float* out){
  int b = blockIdx.x;
  int tid = threadIdx.x;
  int w = tid >> 6, l = tid & 63;
  int kh = l >> 5;               // this lane's k-half
  int j  = 32*w + (l & 31);      // gate row owned by the (l, l+32) pair
  bool lo = (kh == 0);
  int len = lengths[b];

  __shared__ __align__(16) _Float16 hb[2][H_];

  // Weights in registers: rows {j, H+j, 2H+j}, k in [kh*64, kh*64+64)
  half2v Wr[32], Wz[32], Wn[32];
  {
    const float* baseR = &whh[(long)j*H_        + kh*64];
    const float* baseZ = &whh[(long)(H_ + j)*H_ + kh*64];
    const float* baseN = &whh[(long)(2*H_+j)*H_ + kh*64];
    #pragma unroll
    for (int t4 = 0; t4 < 16; t4++){
      float4 vr = *(const float4*)(baseR + t4*4);
      float4 vz = *(const float4*)(baseZ + t4*4);
      float4 vn = *(const float4*)(baseN + t4*4);
      half2v a;
      a[0]=(_Float16)vr.x; a[1]=(_Float16)vr.y; Wr[2*t4] = a;
      a[0]=(_Float16)vr.z; a[1]=(_Float16)vr.w; Wr[2*t4+1] = a;
      a[0]=(_Float16)vz.x; a[1]=(_Float16)vz.y; Wz[2*t4] = a;
      a[0]=(_Float16)vz.z; a[1]=(_Float16)vz.w; Wz[2*t4+1] = a;
      a[0]=(_Float16)vn.x; a[1]=(_Float16)vn.y; Wn[2*t4] = a;
      a[0]=(_Float16)vn.z; a[1]=(_Float16)vn.w; Wn[2*t4+1] = a;
    }
  }
  // Anti-remat pin: opaque asm redefinition forces each weight to stay in an
  // arch VGPR; the loop-invariant global loads can no longer be replayed
  // per-use by the register allocator (rule: remat killed by opaque def).
  #pragma unroll
  for (int i = 0; i < 32; i++){
    unsigned tr = __builtin_bit_cast(unsigned, Wr[i]);
    asm volatile("" : "+v"(tr));
    Wr[i] = __builtin_bit_cast(half2v, tr);
    unsigned tz = __builtin_bit_cast(unsigned, Wz[i]);
    asm volatile("" : "+v"(tz));
    Wz[i] = __builtin_bit_cast(half2v, tz);
    unsigned tn = __builtin_bit_cast(unsigned, Wn[i]);
    asm volatile("" : "+v"(tn));
    Wn[i] = __builtin_bit_cast(half2v, tn);
  }

  float bn_ = bhh[2*H_ + j];
  const _Float16* pr = gi3 + ((long)b*G_ + j)*T_;
  const _Float16* pz = pr + (long)H_*T_;
  const _Float16* pn = pr + (long)2*H_*T_;

  if (tid < H_){ hb[0][tid] = (_Float16)0.0f; hb[1][tid] = (_Float16)0.0f; }

  // gi prefetch: named double-buffer registers, static (no runtime indexing)
  half8 prA, pzA, pnA, prB, pzB, pnB;
  if (lo){
    prA = *(const half8*)pr; pzA = *(const half8*)pz; pnA = *(const half8*)pn;
  }
  __syncthreads();

  float hval = 0.0f;

  auto substeps = [&](half8 cr, half8 cz, half8 cn, int c){
    #pragma unroll
    for (int i = 0; i < 8; i++){
      const int rp = i & 1;            // read hb[rp], write hb[rp^1]
      float ar0=0.0f, ar1=0.0f, az0=0.0f, az1=0.0f, an0=0.0f, an1=0.0f;
      #pragma unroll
      for (int q8 = 0; q8 < 8; q8++){
        half8 hv = *(const half8*)&hb[rp][kh*64 + q8*8];   // 2 addrs/wave, broadcast
        #pragma unroll
        for (int m = 0; m < 4; m++){
          half2v h2; h2[0] = hv[2*m]; h2[1] = hv[2*m+1];
          const int q = q8*4 + m;
          if ((q & 1) == 0){
            ar0 = __builtin_amdgcn_fdot2(h2, Wr[q], ar0, false);
            az0 = __builtin_amdgcn_fdot2(h2, Wz[q], az0, false);
            an0 = __builtin_amdgcn_fdot2(h2, Wn[q], an0, false);
          } else {
            ar1 = __builtin_amdgcn_fdot2(h2, Wr[q], ar1, false);
            az1 = __builtin_amdgcn_fdot2(h2, Wz[q], az1, false);
            an1 = __builtin_amdgcn_fdot2(h2, Wn[q], an1, false);
          }
        }
      }
      float R = ar0 + ar1, Z = az0 + az1, N = an0 + an1;
      R += __shfl_xor(R, 32, 64);      // combine k-halves across the pair
      Z += __shfl_xor(Z, 32, 64);
      N += __shfl_xor(N, 32, 64);
      if (lo){
        float r = fsigmoid((float)cr[i] + R);
        float z = fsigmoid((float)cz[i] + Z);
        float n = ftanh_((float)cn[i] + r*(N + bn_));
        hval = (1.0f - z)*n + z*hval;
        hb[rp^1][j] = (_Float16)hval;
        int t = c*8 + i;
        out[((long)(b*T_ + t))*H_ + j] = (t < len) ? hval : 0.0f;
      }
      BAR();
    }
  };

  for (int c = 0; c < 32; c += 2){
    if (lo){
      int nb = (c+1)*8;
      prB = *(const half8*)(pr+nb); pzB = *(const half8*)(pz+nb); pnB = *(const half8*)(pn+nb);
    }
    substeps(prA, pzA, pnA, c);
    if (lo && c+2 < 32){
      int nb = (c+2)*8;
      prA = *(const half8*)(pr+nb); pzA = *(const half8*)(pz+nb); pnA = *(const half8*)(pn+nb);
    }
    substeps(prB, pzB, pnB, c+1);
  }
}

extern "C" void kernel_launch(void* const* d_in, const int* in_sizes, int n_in,
                              void* d_out, int out_size, void* d_ws, size_t ws_size,
                              hipStream_t stream) {
  char* base = (char*)d_ws;
  size_t off = 0;
  auto alloc = [&](size_t bytes)->void*{
    void* p = base + off; off = (off + bytes + 255) & ~(size_t)255; return p;
  };
  float*     wcol = (float*)alloc((size_t)B_*D_*4);
  _Float16*  gi3  = (_Float16*)alloc((size_t)B_*G_*T_*2);
  if (off > ws_size) return;

  const float* x   = (const float*)d_in[0];
  const float* mm  = (const float*)d_in[1];
  const float* vt  = (const float*)d_in[2];
  const int*   len = (const int*)d_in[4];
  const float* E   = (const float*)d_in[5];
  const float* wih = (const float*)d_in[6];
  const float* whh = (const float*)d_in[7];
  const float* bih = (const float*)d_in[8];
  const float* bhh = (const float*)d_in[9];

  adj_k<<<dim3(B_),dim3(256),0,stream>>>(mm, E, wcol);
  gi_k<<<dim3(256),dim3(512),0,stream>>>(x, mm, vt, E, wih, bih, bhh, wcol, gi3);
  gru_k<<<dim3(B_),dim3(256),0,stream>>>(gi3, whh, bhh, len, (float*)d_out);
}